// Round 19
// baseline (274.780 us; speedup 1.0000x reference)
//
#include <hip/hip_runtime.h>
#include <math.h>

#define NCH 32
#define CHV (64*32*64)      // one channel volume
#define NB 4
#define NT2 512             // tile-slots per n: 32zt * 8yt * 2chh
#define INVC (1.0f/(32.0f+1e-6f))
#define D2R 0.017453292519943295f
#define R2D 57.29577951308232f

// LDS unit (one channel):
//   feat1 slab: 32 rows (8z x 4y) x pitch 73 at [0] (odd pitch, scalar access).
//   feat0 slab: 24 rows (4z x 6y) x pitch 72 at [F0B]; F0B 16B-aligned ->
//     b128 row reads/writes aligned.
// NOTE (r18): the ~1.7e7 SQ_LDS_BANK_CONFLICT is structural to the b128 row
// traffic -- insensitive to feat1 pitch (72 vs 73). Pitch 68 regressed 2x.
// OOB z/y rows staged as ZEROS -> no masking anywhere.
#define P1A 73              // feat1 pitch
#define P1B 72              // feat0 pitch
#define F0B (32*P1A)        // 2336
#define UNITSZ (32*P1A + 24*P1B)   // 4064 floats (16.3 KB); 2 units = 32.5 KB

// ---------------------------------------------------------------------------
// Kernel 1: fused rotate-warp(feat1) x 27-offset correlation vs feat0.
// Block = (b, chh, 2z x 4y x 64x tile): 256 threads.
// Waves 0/1/2 = rotations (-4 / 0 / +4 deg); wave 3 = dedicated stager.
// Double-buffered, 1 barrier/channel. Compute waves touch ONLY LDS.
// ---------------------------------------------------------------------------
__global__ __launch_bounds__(256) void k_heat(const float* __restrict__ feat0,
                                              const float* __restrict__ feat1,
                                              float* __restrict__ partial)
{
    __shared__ float L[2][UNITSZ];

    // XCD-chunked remap: XCD x gets 256 consecutive nids = exactly one (b,chh)
    const int lid = (int)blockIdx.x;            // 0..2047
    const int nid = (lid & 7) * 256 + (lid >> 3);
    const int yt  = nid & 7;
    const int zt  = (nid >> 3) & 31;
    const int chh = (nid >> 8) & 1;
    const int b   = nid >> 9;

    const int tid = (int)threadIdx.x;
    const int wv = tid >> 6;           // 0,1,2 compute rotations; 3 stager
    const int lane = tid & 63;
    const int tx = lane & 15, ty = lane >> 4;
    const int x0 = 4 * tx;
    const int z0 = 2 * zt;             // thread owns z0, z0+1
    const bool ident = (wv == 1);

    const float* f0base = feat0 + ((size_t)b * NCH + chh * 16) * CHV;
    const float* f1base = feat1 + ((size_t)b * NCH + chh * 16) * CHV;

    // ---- bilinear setup (channel-invariant), rot waves 0/2 only ----
    int aB[2][4];
    float wAx[2][4], wBx[2][4], wZl[2][4];
    if (wv == 0 || wv == 2) {
        const float th = 4.0f * (float)(wv - 1) * D2R;
        const float cs = cosf(th), sn = sinf(th);
        #pragma unroll
        for (int k = 0; k < 2; ++k) {
            #pragma unroll
            for (int i = 0; i < 4; ++i) {
                const float rx = (float)(x0 + i) - 31.5f;
                const float rz = (float)(z0 + k) - 31.5f;
                const float sx = cs * rx - sn * rz + 31.5f;
                const float sz = sn * rx + cs * rz + 31.5f;
                const float xf = floorf(sx), zf = floorf(sz);
                const float fx = sx - xf, fz = sz - zf;
                const int ix = (int)xf, iz = (int)zf;
                int bx; float A_, B_;
                if (ix == -1)      { bx = 0;  A_ = fx;        B_ = 0.0f; }
                else if (ix == 63) { bx = 62; A_ = 0.0f;      B_ = 1.0f - fx; }
                else if ((unsigned)ix <= 62u) { bx = ix; A_ = 1.0f - fx; B_ = fx; }
                else               { bx = 0;  A_ = 0.0f;      B_ = 0.0f; }
                wAx[k][i] = A_; wBx[k][i] = B_;
                wZl[k][i] = 1.0f - fz;
                const int zl = min(max(iz - (2 * zt - 3), 0), 6);
                aB[k][i] = (zl * 4 + ty) * P1A + bx;
            }
        }
    }
    const int iA0 = (12 + ty) * P1A + x0;     // identity z0 row (zr=3)
    const int iA1 = iA0 + 4 * P1A;            // identity z0+1 row (zr=4)
    const int fb0 = F0B + ty * P1B + x0;      // feat0 corr base (row j=ty)

    float acc[27];
    #pragma unroll
    for (int o = 0; o < 27; ++o) acc[o] = 0.0f;

#define STAGE_CH(CHN)                                                           \
    {                                                                           \
        const int u_ = (CHN) & 1;                                               \
        const float* f1c_ = f1base + (size_t)(CHN) * CHV;                       \
        const float* f0c_ = f0base + (size_t)(CHN) * CHV;                       \
        float* Ln_ = &L[u_][0];                                                 \
        const int tq_ = lane >> 4, c4_ = (lane & 15) << 2;                      \
        float4 v1_[8], v0_[6];                                                  \
        _Pragma("unroll")                                                       \
        for (int k_ = 0; k_ < 8; ++k_) {                                        \
            const int zs_ = 2 * zt - 3 + k_;                                    \
            v1_[k_] = (float4){0.0f, 0.0f, 0.0f, 0.0f};                         \
            if (zs_ >= 0 && zs_ < 64)                                           \
                v1_[k_] = *(const float4*)(f1c_ + zs_ * 2048                    \
                            + (4 * yt + tq_) * 64 + c4_);                       \
        }                                                                       \
        _Pragma("unroll")                                                       \
        for (int k_ = 0; k_ < 6; ++k_) {                                        \
            const int r_ = 4 * k_ + tq_;                                        \
            const int i_ = (r_ * 43) >> 8;                                      \
            const int j_ = r_ - 6 * i_;                                         \
            const int zf_ = 2 * zt - 1 + i_;                                    \
            const int yf_ = 4 * yt - 1 + j_;                                    \
            v0_[k_] = (float4){0.0f, 0.0f, 0.0f, 0.0f};                         \
            if (zf_ >= 0 && zf_ < 64 && yf_ >= 0 && yf_ < 32)                   \
                v0_[k_] = *(const float4*)(f0c_ + zf_ * 2048 + yf_ * 64 + c4_); \
        }                                                                       \
        _Pragma("unroll")                                                       \
        for (int k_ = 0; k_ < 8; ++k_) {                                        \
            const int w_ = (4 * k_ + tq_) * P1A + c4_;                          \
            Ln_[w_ + 0] = v1_[k_].x; Ln_[w_ + 1] = v1_[k_].y;                   \
            Ln_[w_ + 2] = v1_[k_].z; Ln_[w_ + 3] = v1_[k_].w;                   \
        }                                                                       \
        _Pragma("unroll")                                                       \
        for (int k_ = 0; k_ < 6; ++k_)                                          \
            *(float4*)&Ln_[F0B + (4 * k_ + tq_) * P1B + c4_] = v0_[k_];         \
    }

#define ROWFMA(KK, OZP1, YRI, R)                                                \
    { const int base_ = (OZP1) * 9 + (2 - (YRI)) * 3;                           \
      acc[base_ + 0] += g0[KK]*R.x + fr[KK][0]*R.y + fr[KK][1]*R.z + fr[KK][2]*R.w; \
      acc[base_ + 1] += fr[KK][0]*R.x + fr[KK][1]*R.y + fr[KK][2]*R.z + fr[KK][3]*R.w; \
      acc[base_ + 2] += fr[KK][1]*R.x + fr[KK][2]*R.y + fr[KK][3]*R.z + g5[KK]*R.w; }

    if (wv == 3) STAGE_CH(0)
    __syncthreads();

    #pragma unroll 1
    for (int ch = 0; ch < 16; ++ch) {
        if (wv == 3) {
            if (ch + 1 < 16) STAGE_CH(ch + 1)
        } else {
            const float* Lb = &L[ch & 1][0];

            float fr[2][4];
            if (ident) {
                #pragma unroll
                for (int i = 0; i < 4; ++i) {
                    fr[0][i] = Lb[iA0 + i];
                    fr[1][i] = Lb[iA1 + i];
                }
            } else {
                #pragma unroll
                for (int k = 0; k < 2; ++k) {
                    #pragma unroll
                    for (int i = 0; i < 4; ++i) {
                        const int a = aB[k][i];
                        const float p00 = Lb[a], p01 = Lb[a + 1];
                        const float p10 = Lb[a + 4 * P1A], p11 = Lb[a + 4 * P1A + 1];
                        const float sLo = wAx[k][i] * p00 + wBx[k][i] * p01;
                        const float sHi = wAx[k][i] * p10 + wBx[k][i] * p11;
                        fr[k][i] = sHi + wZl[k][i] * (sLo - sHi);
                    }
                }
            }

            float g0[2], g5[2];
            #pragma unroll
            for (int k = 0; k < 2; ++k) {
                const float a_ = __shfl_up(fr[k][3], 1, 64);
                const float c_ = __shfl_down(fr[k][0], 1, 64);
                g0[k] = (tx == 0) ? 0.0f : a_;
                g5[k] = (tx == 15) ? 0.0f : c_;
            }

            #pragma unroll
            for (int zri = 0; zri < 4; ++zri) {
                const float4 R0 = *(const float4*)&Lb[fb0 + (zri * 6 + 0) * P1B];
                const float4 R1 = *(const float4*)&Lb[fb0 + (zri * 6 + 1) * P1B];
                const float4 R2 = *(const float4*)&Lb[fb0 + (zri * 6 + 2) * P1B];
                if (zri == 0) { ROWFMA(0, 2, 0, R0) ROWFMA(0, 2, 1, R1) ROWFMA(0, 2, 2, R2) }
                if (zri == 1) { ROWFMA(0, 1, 0, R0) ROWFMA(0, 1, 1, R1) ROWFMA(0, 1, 2, R2)
                                ROWFMA(1, 2, 0, R0) ROWFMA(1, 2, 1, R1) ROWFMA(1, 2, 2, R2) }
                if (zri == 2) { ROWFMA(0, 0, 0, R0) ROWFMA(0, 0, 1, R1) ROWFMA(0, 0, 2, R2)
                                ROWFMA(1, 1, 0, R0) ROWFMA(1, 1, 1, R1) ROWFMA(1, 1, 2, R2) }
                if (zri == 3) { ROWFMA(1, 0, 0, R0) ROWFMA(1, 0, 1, R1) ROWFMA(1, 0, 2, R2) }
            }
        }
        __syncthreads();
    }
#undef ROWFMA
#undef STAGE_CH

    if (wv < 3) {
        const int slot = (zt * 8 + yt) * 2 + chh;
        #pragma unroll 1
        for (int o = 0; o < 27; ++o) {
            float v = acc[o];
            #pragma unroll
            for (int d = 32; d >= 1; d >>= 1) v += __shfl_down(v, d, 64);
            if (lane == 0)
                partial[((size_t)((b * 3 + wv) * 27) + o) * NT2 + slot] = v;
        }
    }
}

// ---------------------------------------------------------------------------
// Kernel 2: grid(4) -- one block per batch. Reduce this batch's 81 partial
// rows (512 slots each), run the MLP, emit matrix + warp params + res vector.
// ---------------------------------------------------------------------------
__global__ __launch_bounds__(128) void k_mlp(const float* __restrict__ partial,
                                             const float* __restrict__ W1,
                                             const float* __restrict__ b1,
                                             const float* __restrict__ W2,
                                             const float* __restrict__ b2,
                                             const float* __restrict__ W3,
                                             const float* __restrict__ b3,
                                             float* __restrict__ out,
                                             float* __restrict__ params,
                                             float* __restrict__ resv)
{
    __shared__ float f[81];
    __shared__ float h1[128];
    __shared__ float h2[128];
    __shared__ float denom_s;
    __shared__ float r4[4];
    const int b = (int)blockIdx.x;
    const int tid = (int)threadIdx.x;

    // reduce rows b*81 .. b*81+80 (each 512 floats) -> leaky-relu -> f[]
    if (tid < 81) {
        const float4* p = (const float4*)(partial + ((size_t)b * 81 + tid) * NT2);
        float s0 = 0.f, s1 = 0.f, s2 = 0.f, s3 = 0.f;
        #pragma unroll 4
        for (int i = 0; i < NT2 / 4; ++i) {
            const float4 v = p[i];
            s0 += v.x; s1 += v.y; s2 += v.z; s3 += v.w;
        }
        const float hv = ((s0 + s1) + (s2 + s3)) * INVC;
        f[tid] = (hv >= 0.0f) ? hv : 0.1f * hv;
    }
    __syncthreads();
    if (tid == 0) {
        float ss = 0.0f;
        for (int k = 0; k < 81; ++k) ss += f[k] * f[k];
        denom_s = 1e-6f + sqrtf(ss);
    }
    __syncthreads();
    if (tid < 81) f[tid] = f[tid] / denom_s;
    __syncthreads();
    {
        float a = b1[tid];
        const float* wr = W1 + tid * 81;
        for (int k = 0; k < 81; ++k) a += wr[k] * f[k];
        h1[tid] = (a >= 0.0f) ? a : 0.1f * a;
    }
    __syncthreads();
    {
        float a = b2[tid];
        const float* wr = W2 + tid * 128;
        for (int k = 0; k < 128; ++k) a += wr[k] * h1[k];
        h2[tid] = (a >= 0.0f) ? a : 0.1f * a;
    }
    __syncthreads();
    if (tid < 4) {
        float a = b3[tid];
        const float* wr = W3 + tid * 128;
        for (int k = 0; k < 128; ++k) a += wr[k] * h2[k];
        r4[tid] = a;
    }
    __syncthreads();
    if (tid == 0) {
        const float r_out = r4[0], yv = r4[1], xv = r4[2], zv = r4[3];
        const float t2 = r_out * D2R;
        const float c2 = cosf(t2), s2 = sinf(t2);
        float* m = out + 1 + b * 16;
        m[0] = c2;  m[1] = 0.0f; m[2] = s2;  m[3] = -xv;
        m[4] = 0.0f; m[5] = 1.0f; m[6] = 0.0f; m[7] = -yv;
        m[8] = -s2; m[9] = 0.0f; m[10] = c2; m[11] = -zv;
        m[12] = 0.0f; m[13] = 0.0f; m[14] = 0.0f; m[15] = 1.0f;
        params[b * 8 + 0] = c2;
        params[b * 8 + 1] = s2;
        params[b * 8 + 2] = c2 * xv - s2 * zv;
        params[b * 8 + 3] = yv;
        params[b * 8 + 4] = s2 * xv + c2 * zv;
        resv[b * 4 + 0] = -xv;
        resv[b * 4 + 1] = -yv;
        resv[b * 4 + 2] = -zv;
        resv[b * 4 + 3] = atan2f(s2, c2) * R2D;
    }
}

// ---------------------------------------------------------------------------
// Kernel 2.5: scalar loss from resv + ground truth.
// ---------------------------------------------------------------------------
__global__ __launch_bounds__(64) void k_loss(const float* __restrict__ resv,
                                             const float* __restrict__ camg,
                                             float* __restrict__ out)
{
    if (threadIdx.x == 0) {
        float tl2 = 0.0f, dl2 = 0.0f;
        for (int b = 0; b < NB; ++b) {
            const float* g = camg + b * 16;
            const float dx = resv[b * 4 + 0] - g[3];
            const float dy = resv[b * 4 + 1] - g[7];
            const float dz = resv[b * 4 + 2] - g[11];
            tl2 += dx * dx + dy * dy + dz * dz;
            const float dg = atan2f(g[2], g[10]) * R2D;
            const float dd = resv[b * 4 + 3] - dg;
            dl2 += dd * dd;
        }
        out[0] = tl2 * 0.25f + dl2 * 0.25f;
    }
}

// ---------------------------------------------------------------------------
// Kernel 3: warp feat1 by estimated transform -> feat1_warped (d_out + 65).
// 4 x-voxels per thread: dwordx4 stores, amortized addressing; XCD-chunked
// block remap for L2 locality of the gathers.
// ---------------------------------------------------------------------------
__global__ __launch_bounds__(256) void k_warp(const float* __restrict__ feat1,
                                              const float* __restrict__ params,
                                              float* __restrict__ outw)
{
    // 512 blocks total; XCD remap: XCD x gets 64 consecutive nids.
    const int flat = (int)blockIdx.y * 128 + (int)blockIdx.x;   // 0..511
    const int nid = (flat & 7) * 64 + (flat >> 3);
    const int b = nid >> 7;                    // 0..3
    const int pblk = nid & 127;                // 0..127

    const int tid = (int)threadIdx.x;
    const int p0 = (pblk * 256 + tid) * 4;     // first of 4 x-voxels
    const int z = p0 >> 11;
    const int y = (p0 >> 6) & 31;
    const int x0 = p0 & 63;

    const float cs = params[b * 8 + 0], sn = params[b * 8 + 1];
    const float tpx = params[b * 8 + 2], tpy = params[b * 8 + 3], tpz = params[b * 8 + 4];

    const float ry = (float)y - 15.5f;
    const float rz = (float)z - 31.5f;
    const float sy = ry + tpy + 15.5f;
    const float yf = floorf(sy);
    const float fy = sy - yf;
    const int iy = (int)yf;
    const float wy[2] = {1.0f - fy, fy};
    const int ys[2] = {min(max(iy, 0), 31), min(max(iy + 1, 0), 31)};
    const bool vy[2] = {(unsigned)iy < 32u, (unsigned)(iy + 1) < 32u};

    int idx[4][8]; float w[4][8];
    #pragma unroll
    for (int i = 0; i < 4; ++i) {
        const float rx = (float)(x0 + i) - 31.5f;
        const float sx = cs * rx - sn * rz + tpx + 31.5f;
        const float sz = sn * rx + cs * rz + tpz + 31.5f;
        const float xf = floorf(sx), zf = floorf(sz);
        const float fx = sx - xf, fz = sz - zf;
        const int ix = (int)xf, iz = (int)zf;
        const float wx[2] = {1.0f - fx, fx};
        const float wz[2] = {1.0f - fz, fz};
        const int xs[2] = {min(max(ix, 0), 63), min(max(ix + 1, 0), 63)};
        const int zs[2] = {min(max(iz, 0), 63), min(max(iz + 1, 0), 63)};
        const bool vx[2] = {(unsigned)ix < 64u, (unsigned)(ix + 1) < 64u};
        const bool vz[2] = {(unsigned)iz < 64u, (unsigned)(iz + 1) < 64u};
        int q = 0;
        #pragma unroll
        for (int dz = 0; dz < 2; ++dz)
            #pragma unroll
            for (int dy = 0; dy < 2; ++dy)
                #pragma unroll
                for (int dx = 0; dx < 2; ++dx) {
                    idx[i][q] = zs[dz] * 2048 + ys[dy] * 64 + xs[dx];
                    w[i][q] = (vx[dx] && vy[dy] && vz[dz])
                              ? wx[dx] * wy[dy] * wz[dz] : 0.0f;
                    ++q;
                }
    }

    const float* f1b = feat1 + (size_t)b * NCH * CHV;
    float* ob = outw + (size_t)b * NCH * CHV;
    #pragma unroll 1
    for (int c = 0; c < NCH; ++c) {
        const float* f1c = f1b + (size_t)c * CHV;
        float4 r;
        float* rp = (float*)&r;
        #pragma unroll
        for (int i = 0; i < 4; ++i) {
            float a = 0.0f;
            #pragma unroll
            for (int k = 0; k < 8; ++k) a += w[i][k] * f1c[idx[i][k]];
            rp[i] = a;
        }
        *(float4*)(ob + (size_t)c * CHV + p0) = r;
    }
}

// ---------------------------------------------------------------------------
extern "C" void kernel_launch(void* const* d_in, const int* in_sizes, int n_in,
                              void* d_out, int out_size, void* d_ws, size_t ws_size,
                              hipStream_t stream)
{
    (void)in_sizes; (void)n_in; (void)out_size; (void)ws_size;
    const float* feat0 = (const float*)d_in[0];
    const float* feat1 = (const float*)d_in[1];
    const float* camg  = (const float*)d_in[2];
    const float* W1 = (const float*)d_in[3];
    const float* b1 = (const float*)d_in[4];
    const float* W2 = (const float*)d_in[5];
    const float* b2 = (const float*)d_in[6];
    const float* W3 = (const float*)d_in[7];
    const float* b3 = (const float*)d_in[8];
    float* out = (float*)d_out;

    float* partial = (float*)d_ws;                 // 324*512 floats ~ 663 KB
    float* params  = partial + 324 * NT2;          // 32 floats
    float* resv    = params + 32;                  // 16 floats

    hipLaunchKernelGGL(k_heat, dim3(2048), dim3(256), 0, stream,
                       feat0, feat1, partial);
    hipLaunchKernelGGL(k_mlp, dim3(4), dim3(128), 0, stream,
                       partial, W1, b1, W2, b2, W3, b3, out, params, resv);
    hipLaunchKernelGGL(k_loss, dim3(1), dim3(64), 0, stream, resv, camg, out);
    hipLaunchKernelGGL(k_warp, dim3(128, 4), dim3(256), 0, stream,
                       feat1, params, out + 65);
}

// Round 20
// 190.164 us; speedup vs baseline: 1.4450x; 1.4450x over previous
//
#include <hip/hip_runtime.h>
#include <math.h>

#define NCH 32
#define CHV (64*32*64)      // one channel volume
#define NB 4
#define NT2 512             // tile-slots per n: 32zt * 8yt * 2chh
#define INVC (1.0f/(32.0f+1e-6f))
#define D2R 0.017453292519943295f
#define R2D 57.29577951308232f

// LDS unit (one channel):
//   feat1 slab: 32 rows (8z x 4y) x pitch 73 at [0] (odd pitch, scalar access).
//   feat0 slab: 24 rows (4z x 6y) x pitch 72 at [F0B]; F0B 16B-aligned ->
//     b128 row reads/writes aligned.
// NOTE (r18): the ~1.7e7 SQ_LDS_BANK_CONFLICT is structural to the b128 row
// traffic -- insensitive to feat1 pitch (72 vs 73). Pitch 68 regressed 2x.
// OOB z/y rows staged as ZEROS -> no masking anywhere.
#define P1A 73              // feat1 pitch
#define P1B 72              // feat0 pitch
#define F0B (32*P1A)        // 2336
#define UNITSZ (32*P1A + 24*P1B)   // 4064 floats (16.3 KB); 2 units = 32.5 KB

// ---------------------------------------------------------------------------
// Kernel 1: fused rotate-warp(feat1) x 27-offset correlation vs feat0.
// Block = (b, chh, 2z x 4y x 64x tile): 256 threads.
// Waves 0/1/2 = rotations (-4 / 0 / +4 deg); wave 3 = dedicated stager.
// Double-buffered, 1 barrier/channel. Compute waves touch ONLY LDS.
// ---------------------------------------------------------------------------
__global__ __launch_bounds__(256) void k_heat(const float* __restrict__ feat0,
                                              const float* __restrict__ feat1,
                                              float* __restrict__ partial)
{
    __shared__ float L[2][UNITSZ];

    // XCD-chunked remap: XCD x gets 256 consecutive nids = exactly one (b,chh)
    const int lid = (int)blockIdx.x;            // 0..2047
    const int nid = (lid & 7) * 256 + (lid >> 3);
    const int yt  = nid & 7;
    const int zt  = (nid >> 3) & 31;
    const int chh = (nid >> 8) & 1;
    const int b   = nid >> 9;

    const int tid = (int)threadIdx.x;
    const int wv = tid >> 6;           // 0,1,2 compute rotations; 3 stager
    const int lane = tid & 63;
    const int tx = lane & 15, ty = lane >> 4;
    const int x0 = 4 * tx;
    const int z0 = 2 * zt;             // thread owns z0, z0+1
    const bool ident = (wv == 1);

    const float* f0base = feat0 + ((size_t)b * NCH + chh * 16) * CHV;
    const float* f1base = feat1 + ((size_t)b * NCH + chh * 16) * CHV;

    // ---- bilinear setup (channel-invariant), rot waves 0/2 only ----
    int aB[2][4];
    float wAx[2][4], wBx[2][4], wZl[2][4];
    if (wv == 0 || wv == 2) {
        const float th = 4.0f * (float)(wv - 1) * D2R;
        const float cs = cosf(th), sn = sinf(th);
        #pragma unroll
        for (int k = 0; k < 2; ++k) {
            #pragma unroll
            for (int i = 0; i < 4; ++i) {
                const float rx = (float)(x0 + i) - 31.5f;
                const float rz = (float)(z0 + k) - 31.5f;
                const float sx = cs * rx - sn * rz + 31.5f;
                const float sz = sn * rx + cs * rz + 31.5f;
                const float xf = floorf(sx), zf = floorf(sz);
                const float fx = sx - xf, fz = sz - zf;
                const int ix = (int)xf, iz = (int)zf;
                int bx; float A_, B_;
                if (ix == -1)      { bx = 0;  A_ = fx;        B_ = 0.0f; }
                else if (ix == 63) { bx = 62; A_ = 0.0f;      B_ = 1.0f - fx; }
                else if ((unsigned)ix <= 62u) { bx = ix; A_ = 1.0f - fx; B_ = fx; }
                else               { bx = 0;  A_ = 0.0f;      B_ = 0.0f; }
                wAx[k][i] = A_; wBx[k][i] = B_;
                wZl[k][i] = 1.0f - fz;
                const int zl = min(max(iz - (2 * zt - 3), 0), 6);
                aB[k][i] = (zl * 4 + ty) * P1A + bx;
            }
        }
    }
    const int iA0 = (12 + ty) * P1A + x0;     // identity z0 row (zr=3)
    const int iA1 = iA0 + 4 * P1A;            // identity z0+1 row (zr=4)
    const int fb0 = F0B + ty * P1B + x0;      // feat0 corr base (row j=ty)

    float acc[27];
    #pragma unroll
    for (int o = 0; o < 27; ++o) acc[o] = 0.0f;

#define STAGE_CH(CHN)                                                           \
    {                                                                           \
        const int u_ = (CHN) & 1;                                               \
        const float* f1c_ = f1base + (size_t)(CHN) * CHV;                       \
        const float* f0c_ = f0base + (size_t)(CHN) * CHV;                       \
        float* Ln_ = &L[u_][0];                                                 \
        const int tq_ = lane >> 4, c4_ = (lane & 15) << 2;                      \
        float4 v1_[8], v0_[6];                                                  \
        _Pragma("unroll")                                                       \
        for (int k_ = 0; k_ < 8; ++k_) {                                        \
            const int zs_ = 2 * zt - 3 + k_;                                    \
            v1_[k_] = (float4){0.0f, 0.0f, 0.0f, 0.0f};                         \
            if (zs_ >= 0 && zs_ < 64)                                           \
                v1_[k_] = *(const float4*)(f1c_ + zs_ * 2048                    \
                            + (4 * yt + tq_) * 64 + c4_);                       \
        }                                                                       \
        _Pragma("unroll")                                                       \
        for (int k_ = 0; k_ < 6; ++k_) {                                        \
            const int r_ = 4 * k_ + tq_;                                        \
            const int i_ = (r_ * 43) >> 8;                                      \
            const int j_ = r_ - 6 * i_;                                         \
            const int zf_ = 2 * zt - 1 + i_;                                    \
            const int yf_ = 4 * yt - 1 + j_;                                    \
            v0_[k_] = (float4){0.0f, 0.0f, 0.0f, 0.0f};                         \
            if (zf_ >= 0 && zf_ < 64 && yf_ >= 0 && yf_ < 32)                   \
                v0_[k_] = *(const float4*)(f0c_ + zf_ * 2048 + yf_ * 64 + c4_); \
        }                                                                       \
        _Pragma("unroll")                                                       \
        for (int k_ = 0; k_ < 8; ++k_) {                                        \
            const int w_ = (4 * k_ + tq_) * P1A + c4_;                          \
            Ln_[w_ + 0] = v1_[k_].x; Ln_[w_ + 1] = v1_[k_].y;                   \
            Ln_[w_ + 2] = v1_[k_].z; Ln_[w_ + 3] = v1_[k_].w;                   \
        }                                                                       \
        _Pragma("unroll")                                                       \
        for (int k_ = 0; k_ < 6; ++k_)                                          \
            *(float4*)&Ln_[F0B + (4 * k_ + tq_) * P1B + c4_] = v0_[k_];         \
    }

#define ROWFMA(KK, OZP1, YRI, R)                                                \
    { const int base_ = (OZP1) * 9 + (2 - (YRI)) * 3;                           \
      acc[base_ + 0] += g0[KK]*R.x + fr[KK][0]*R.y + fr[KK][1]*R.z + fr[KK][2]*R.w; \
      acc[base_ + 1] += fr[KK][0]*R.x + fr[KK][1]*R.y + fr[KK][2]*R.z + fr[KK][3]*R.w; \
      acc[base_ + 2] += fr[KK][1]*R.x + fr[KK][2]*R.y + fr[KK][3]*R.z + g5[KK]*R.w; }

    if (wv == 3) STAGE_CH(0)
    __syncthreads();

    #pragma unroll 1
    for (int ch = 0; ch < 16; ++ch) {
        if (wv == 3) {
            if (ch + 1 < 16) STAGE_CH(ch + 1)
        } else {
            const float* Lb = &L[ch & 1][0];

            float fr[2][4];
            if (ident) {
                #pragma unroll
                for (int i = 0; i < 4; ++i) {
                    fr[0][i] = Lb[iA0 + i];
                    fr[1][i] = Lb[iA1 + i];
                }
            } else {
                #pragma unroll
                for (int k = 0; k < 2; ++k) {
                    #pragma unroll
                    for (int i = 0; i < 4; ++i) {
                        const int a = aB[k][i];
                        const float p00 = Lb[a], p01 = Lb[a + 1];
                        const float p10 = Lb[a + 4 * P1A], p11 = Lb[a + 4 * P1A + 1];
                        const float sLo = wAx[k][i] * p00 + wBx[k][i] * p01;
                        const float sHi = wAx[k][i] * p10 + wBx[k][i] * p11;
                        fr[k][i] = sHi + wZl[k][i] * (sLo - sHi);
                    }
                }
            }

            float g0[2], g5[2];
            #pragma unroll
            for (int k = 0; k < 2; ++k) {
                const float a_ = __shfl_up(fr[k][3], 1, 64);
                const float c_ = __shfl_down(fr[k][0], 1, 64);
                g0[k] = (tx == 0) ? 0.0f : a_;
                g5[k] = (tx == 15) ? 0.0f : c_;
            }

            __builtin_amdgcn_s_setprio(1);
            #pragma unroll
            for (int zri = 0; zri < 4; ++zri) {
                const float4 R0 = *(const float4*)&Lb[fb0 + (zri * 6 + 0) * P1B];
                const float4 R1 = *(const float4*)&Lb[fb0 + (zri * 6 + 1) * P1B];
                const float4 R2 = *(const float4*)&Lb[fb0 + (zri * 6 + 2) * P1B];
                if (zri == 0) { ROWFMA(0, 2, 0, R0) ROWFMA(0, 2, 1, R1) ROWFMA(0, 2, 2, R2) }
                if (zri == 1) { ROWFMA(0, 1, 0, R0) ROWFMA(0, 1, 1, R1) ROWFMA(0, 1, 2, R2)
                                ROWFMA(1, 2, 0, R0) ROWFMA(1, 2, 1, R1) ROWFMA(1, 2, 2, R2) }
                if (zri == 2) { ROWFMA(0, 0, 0, R0) ROWFMA(0, 0, 1, R1) ROWFMA(0, 0, 2, R2)
                                ROWFMA(1, 1, 0, R0) ROWFMA(1, 1, 1, R1) ROWFMA(1, 1, 2, R2) }
                if (zri == 3) { ROWFMA(1, 0, 0, R0) ROWFMA(1, 0, 1, R1) ROWFMA(1, 0, 2, R2) }
            }
            __builtin_amdgcn_s_setprio(0);
        }
        __syncthreads();
    }
#undef ROWFMA
#undef STAGE_CH

    if (wv < 3) {
        const int slot = (zt * 8 + yt) * 2 + chh;
        #pragma unroll 1
        for (int o = 0; o < 27; ++o) {
            float v = acc[o];
            #pragma unroll
            for (int d = 32; d >= 1; d >>= 1) v += __shfl_down(v, d, 64);
            if (lane == 0)
                partial[((size_t)((b * 3 + wv) * 27) + o) * NT2 + slot] = v;
        }
    }
}

// ---------------------------------------------------------------------------
// Kernel 2: grid(4) -- one block per batch. Reduce this batch's 81 partial
// rows (512 slots each), run the MLP, emit matrix + warp params + res vector.
// ---------------------------------------------------------------------------
__global__ __launch_bounds__(128) void k_mlp(const float* __restrict__ partial,
                                             const float* __restrict__ W1,
                                             const float* __restrict__ b1,
                                             const float* __restrict__ W2,
                                             const float* __restrict__ b2,
                                             const float* __restrict__ W3,
                                             const float* __restrict__ b3,
                                             float* __restrict__ out,
                                             float* __restrict__ params,
                                             float* __restrict__ resv)
{
    __shared__ float f[81];
    __shared__ float h1[128];
    __shared__ float h2[128];
    __shared__ float denom_s;
    __shared__ float r4[4];
    const int b = (int)blockIdx.x;
    const int tid = (int)threadIdx.x;

    if (tid < 81) {
        const float4* p = (const float4*)(partial + ((size_t)b * 81 + tid) * NT2);
        float s0 = 0.f, s1 = 0.f, s2 = 0.f, s3 = 0.f;
        #pragma unroll 4
        for (int i = 0; i < NT2 / 4; ++i) {
            const float4 v = p[i];
            s0 += v.x; s1 += v.y; s2 += v.z; s3 += v.w;
        }
        const float hv = ((s0 + s1) + (s2 + s3)) * INVC;
        f[tid] = (hv >= 0.0f) ? hv : 0.1f * hv;
    }
    __syncthreads();
    if (tid == 0) {
        float ss = 0.0f;
        for (int k = 0; k < 81; ++k) ss += f[k] * f[k];
        denom_s = 1e-6f + sqrtf(ss);
    }
    __syncthreads();
    if (tid < 81) f[tid] = f[tid] / denom_s;
    __syncthreads();
    {
        float a = b1[tid];
        const float* wr = W1 + tid * 81;
        for (int k = 0; k < 81; ++k) a += wr[k] * f[k];
        h1[tid] = (a >= 0.0f) ? a : 0.1f * a;
    }
    __syncthreads();
    {
        float a = b2[tid];
        const float* wr = W2 + tid * 128;
        for (int k = 0; k < 128; ++k) a += wr[k] * h1[k];
        h2[tid] = (a >= 0.0f) ? a : 0.1f * a;
    }
    __syncthreads();
    if (tid < 4) {
        float a = b3[tid];
        const float* wr = W3 + tid * 128;
        for (int k = 0; k < 128; ++k) a += wr[k] * h2[k];
        r4[tid] = a;
    }
    __syncthreads();
    if (tid == 0) {
        const float r_out = r4[0], yv = r4[1], xv = r4[2], zv = r4[3];
        const float t2 = r_out * D2R;
        const float c2 = cosf(t2), s2 = sinf(t2);
        float* m = out + 1 + b * 16;
        m[0] = c2;  m[1] = 0.0f; m[2] = s2;  m[3] = -xv;
        m[4] = 0.0f; m[5] = 1.0f; m[6] = 0.0f; m[7] = -yv;
        m[8] = -s2; m[9] = 0.0f; m[10] = c2; m[11] = -zv;
        m[12] = 0.0f; m[13] = 0.0f; m[14] = 0.0f; m[15] = 1.0f;
        params[b * 8 + 0] = c2;
        params[b * 8 + 1] = s2;
        params[b * 8 + 2] = c2 * xv - s2 * zv;
        params[b * 8 + 3] = yv;
        params[b * 8 + 4] = s2 * xv + c2 * zv;
        resv[b * 4 + 0] = -xv;
        resv[b * 4 + 1] = -yv;
        resv[b * 4 + 2] = -zv;
        resv[b * 4 + 3] = atan2f(s2, c2) * R2D;
    }
}

// ---------------------------------------------------------------------------
// Kernel 2.5: scalar loss from resv + ground truth.
// ---------------------------------------------------------------------------
__global__ __launch_bounds__(64) void k_loss(const float* __restrict__ resv,
                                             const float* __restrict__ camg,
                                             float* __restrict__ out)
{
    if (threadIdx.x == 0) {
        float tl2 = 0.0f, dl2 = 0.0f;
        for (int b = 0; b < NB; ++b) {
            const float* g = camg + b * 16;
            const float dx = resv[b * 4 + 0] - g[3];
            const float dy = resv[b * 4 + 1] - g[7];
            const float dz = resv[b * 4 + 2] - g[11];
            tl2 += dx * dx + dy * dy + dz * dz;
            const float dg = atan2f(g[2], g[10]) * R2D;
            const float dd = resv[b * 4 + 3] - dg;
            dl2 += dd * dd;
        }
        out[0] = tl2 * 0.25f + dl2 * 0.25f;
    }
}

// ---------------------------------------------------------------------------
// Kernel 3: warp feat1 by estimated transform -> feat1_warped (d_out + 65).
// 1 voxel/thread (r18 config: low VGPR + 524k threads = latency hiding; the
// r19 4-voxel variant blew registers and lost 4x parallelism -> 2.7x slower).
// ---------------------------------------------------------------------------
__global__ __launch_bounds__(256) void k_warp(const float* __restrict__ feat1,
                                              const float* __restrict__ params,
                                              float* __restrict__ outw)
{
    const int b = blockIdx.y;
    const int p = (int)blockIdx.x * 256 + (int)threadIdx.x;
    const int z = p >> 11;
    const int y = (p >> 6) & 31;
    const int x = p & 63;

    const float cs = params[b * 8 + 0], sn = params[b * 8 + 1];
    const float tpx = params[b * 8 + 2], tpy = params[b * 8 + 3], tpz = params[b * 8 + 4];

    const float rx = (float)x - 31.5f;
    const float ry = (float)y - 15.5f;
    const float rz = (float)z - 31.5f;
    const float sx = cs * rx - sn * rz + tpx + 31.5f;
    const float sy = ry + tpy + 15.5f;
    const float sz = sn * rx + cs * rz + tpz + 31.5f;

    const float xf = floorf(sx), yf = floorf(sy), zf = floorf(sz);
    const float fx = sx - xf, fy = sy - yf, fz = sz - zf;
    const int ix = (int)xf, iy = (int)yf, iz = (int)zf;

    const float wx[2] = {1.0f - fx, fx};
    const float wy[2] = {1.0f - fy, fy};
    const float wz[2] = {1.0f - fz, fz};
    const int xs[2] = {min(max(ix, 0), 63), min(max(ix + 1, 0), 63)};
    const int ys[2] = {min(max(iy, 0), 31), min(max(iy + 1, 0), 31)};
    const int zs[2] = {min(max(iz, 0), 63), min(max(iz + 1, 0), 63)};
    const bool vx[2] = {(unsigned)ix < 64u, (unsigned)(ix + 1) < 64u};
    const bool vy[2] = {(unsigned)iy < 32u, (unsigned)(iy + 1) < 32u};
    const bool vz[2] = {(unsigned)iz < 64u, (unsigned)(iz + 1) < 64u};

    int idx[8]; float w[8];
    int q = 0;
    #pragma unroll
    for (int dz = 0; dz < 2; ++dz)
        #pragma unroll
        for (int dy = 0; dy < 2; ++dy)
            #pragma unroll
            for (int dx = 0; dx < 2; ++dx) {
                idx[q] = zs[dz] * 2048 + ys[dy] * 64 + xs[dx];
                w[q] = (vx[dx] && vy[dy] && vz[dz]) ? wx[dx] * wy[dy] * wz[dz] : 0.0f;
                ++q;
            }

    const float* f1b = feat1 + (size_t)b * NCH * CHV;
    float* ob = outw + (size_t)b * NCH * CHV;
    #pragma unroll 2
    for (int c = 0; c < NCH; ++c) {
        const float* f1c = f1b + (size_t)c * CHV;
        float a = 0.0f;
        #pragma unroll
        for (int k = 0; k < 8; ++k) a += w[k] * f1c[idx[k]];
        ob[(size_t)c * CHV + p] = a;
    }
}

// ---------------------------------------------------------------------------
extern "C" void kernel_launch(void* const* d_in, const int* in_sizes, int n_in,
                              void* d_out, int out_size, void* d_ws, size_t ws_size,
                              hipStream_t stream)
{
    (void)in_sizes; (void)n_in; (void)out_size; (void)ws_size;
    const float* feat0 = (const float*)d_in[0];
    const float* feat1 = (const float*)d_in[1];
    const float* camg  = (const float*)d_in[2];
    const float* W1 = (const float*)d_in[3];
    const float* b1 = (const float*)d_in[4];
    const float* W2 = (const float*)d_in[5];
    const float* b2 = (const float*)d_in[6];
    const float* W3 = (const float*)d_in[7];
    const float* b3 = (const float*)d_in[8];
    float* out = (float*)d_out;

    float* partial = (float*)d_ws;                 // 324*512 floats ~ 663 KB
    float* params  = partial + 324 * NT2;          // 32 floats
    float* resv    = params + 32;                  // 16 floats

    hipLaunchKernelGGL(k_heat, dim3(2048), dim3(256), 0, stream,
                       feat0, feat1, partial);
    hipLaunchKernelGGL(k_mlp, dim3(4), dim3(128), 0, stream,
                       partial, W1, b1, W2, b2, W3, b3, out, params, resv);
    hipLaunchKernelGGL(k_loss, dim3(1), dim3(64), 0, stream, resv, camg, out);
    dim3 g3((64*32*64) / 256, NB);
    hipLaunchKernelGGL(k_warp, g3, dim3(256), 0, stream, feat1, params, out + 65);
}

// Round 21
// 184.031 us; speedup vs baseline: 1.4931x; 1.0333x over previous
//
#include <hip/hip_runtime.h>
#include <math.h>

#define NCH 32
#define CHV (64*32*64)      // one channel volume
#define NB 4
#define NT2 512             // tile-slots per n: 32zt * 8yt * 2chh
#define INVC (1.0f/(32.0f+1e-6f))
#define D2R 0.017453292519943295f
#define R2D 57.29577951308232f

// LDS unit (one channel):
//   feat1 slab: 32 rows (8z x 4y) x pitch 73 at [0] (odd pitch, scalar access).
//   feat0 slab: 24 rows (4z x 6y) x pitch 72 at [F0B]; F0B 16B-aligned ->
//     b128 row reads/writes aligned.
// NOTE (r18): the ~1.7e7 SQ_LDS_BANK_CONFLICT is structural to the b128 row
// traffic -- insensitive to feat1 pitch (72 vs 73). Pitch 68 regressed 2x.
// OOB z/y rows staged as ZEROS -> no masking anywhere.
#define P1A 73              // feat1 pitch
#define P1B 72              // feat0 pitch
#define F0B (32*P1A)        // 2336
#define UNITSZ (32*P1A + 24*P1B)   // 4064 floats (16.3 KB); 2 units = 32.5 KB

// ---------------------------------------------------------------------------
// Kernel 1: fused rotate-warp(feat1) x 27-offset correlation vs feat0.
// Block = (b, chh, 2z x 4y x 64x tile): 256 threads.
// Waves 0/1/2 = rotations (-4 / 0 / +4 deg); wave 3 = dedicated stager.
// Double-buffered, 1 barrier/channel. Compute waves touch ONLY LDS.
// Structural floor: VGPR=100 (65..128 class) caps HW at 4 waves/SIMD; with
// 4 co-resident blocks we are AT that cap. VALU ~48%, LDS ~50% busy.
// ---------------------------------------------------------------------------
__global__ __launch_bounds__(256) void k_heat(const float* __restrict__ feat0,
                                              const float* __restrict__ feat1,
                                              float* __restrict__ partial)
{
    __shared__ float L[2][UNITSZ];

    // XCD-chunked remap: XCD x gets 256 consecutive nids = exactly one (b,chh)
    const int lid = (int)blockIdx.x;            // 0..2047
    const int nid = (lid & 7) * 256 + (lid >> 3);
    const int yt  = nid & 7;
    const int zt  = (nid >> 3) & 31;
    const int chh = (nid >> 8) & 1;
    const int b   = nid >> 9;

    const int tid = (int)threadIdx.x;
    const int wv = tid >> 6;           // 0,1,2 compute rotations; 3 stager
    const int lane = tid & 63;
    const int tx = lane & 15, ty = lane >> 4;
    const int x0 = 4 * tx;
    const int z0 = 2 * zt;             // thread owns z0, z0+1
    const bool ident = (wv == 1);

    const float* f0base = feat0 + ((size_t)b * NCH + chh * 16) * CHV;
    const float* f1base = feat1 + ((size_t)b * NCH + chh * 16) * CHV;

    // ---- bilinear setup (channel-invariant), rot waves 0/2 only ----
    int aB[2][4];
    float wAx[2][4], wBx[2][4], wZl[2][4];
    if (wv == 0 || wv == 2) {
        const float th = 4.0f * (float)(wv - 1) * D2R;
        const float cs = cosf(th), sn = sinf(th);
        #pragma unroll
        for (int k = 0; k < 2; ++k) {
            #pragma unroll
            for (int i = 0; i < 4; ++i) {
                const float rx = (float)(x0 + i) - 31.5f;
                const float rz = (float)(z0 + k) - 31.5f;
                const float sx = cs * rx - sn * rz + 31.5f;
                const float sz = sn * rx + cs * rz + 31.5f;
                const float xf = floorf(sx), zf = floorf(sz);
                const float fx = sx - xf, fz = sz - zf;
                const int ix = (int)xf, iz = (int)zf;
                int bx; float A_, B_;
                if (ix == -1)      { bx = 0;  A_ = fx;        B_ = 0.0f; }
                else if (ix == 63) { bx = 62; A_ = 0.0f;      B_ = 1.0f - fx; }
                else if ((unsigned)ix <= 62u) { bx = ix; A_ = 1.0f - fx; B_ = fx; }
                else               { bx = 0;  A_ = 0.0f;      B_ = 0.0f; }
                wAx[k][i] = A_; wBx[k][i] = B_;
                wZl[k][i] = 1.0f - fz;
                const int zl = min(max(iz - (2 * zt - 3), 0), 6);
                aB[k][i] = (zl * 4 + ty) * P1A + bx;
            }
        }
    }
    const int iA0 = (12 + ty) * P1A + x0;     // identity z0 row (zr=3)
    const int iA1 = iA0 + 4 * P1A;            // identity z0+1 row (zr=4)
    const int fb0 = F0B + ty * P1B + x0;      // feat0 corr base (row j=ty)

    float acc[27];
    #pragma unroll
    for (int o = 0; o < 27; ++o) acc[o] = 0.0f;

#define STAGE_CH(CHN)                                                           \
    {                                                                           \
        const int u_ = (CHN) & 1;                                               \
        const float* f1c_ = f1base + (size_t)(CHN) * CHV;                       \
        const float* f0c_ = f0base + (size_t)(CHN) * CHV;                       \
        float* Ln_ = &L[u_][0];                                                 \
        const int tq_ = lane >> 4, c4_ = (lane & 15) << 2;                      \
        float4 v1_[8], v0_[6];                                                  \
        _Pragma("unroll")                                                       \
        for (int k_ = 0; k_ < 8; ++k_) {                                        \
            const int zs_ = 2 * zt - 3 + k_;                                    \
            v1_[k_] = (float4){0.0f, 0.0f, 0.0f, 0.0f};                         \
            if (zs_ >= 0 && zs_ < 64)                                           \
                v1_[k_] = *(const float4*)(f1c_ + zs_ * 2048                    \
                            + (4 * yt + tq_) * 64 + c4_);                       \
        }                                                                       \
        _Pragma("unroll")                                                       \
        for (int k_ = 0; k_ < 6; ++k_) {                                        \
            const int r_ = 4 * k_ + tq_;                                        \
            const int i_ = (r_ * 43) >> 8;                                      \
            const int j_ = r_ - 6 * i_;                                         \
            const int zf_ = 2 * zt - 1 + i_;                                    \
            const int yf_ = 4 * yt - 1 + j_;                                    \
            v0_[k_] = (float4){0.0f, 0.0f, 0.0f, 0.0f};                         \
            if (zf_ >= 0 && zf_ < 64 && yf_ >= 0 && yf_ < 32)                   \
                v0_[k_] = *(const float4*)(f0c_ + zf_ * 2048 + yf_ * 64 + c4_); \
        }                                                                       \
        _Pragma("unroll")                                                       \
        for (int k_ = 0; k_ < 8; ++k_) {                                        \
            const int w_ = (4 * k_ + tq_) * P1A + c4_;                          \
            Ln_[w_ + 0] = v1_[k_].x; Ln_[w_ + 1] = v1_[k_].y;                   \
            Ln_[w_ + 2] = v1_[k_].z; Ln_[w_ + 3] = v1_[k_].w;                   \
        }                                                                       \
        _Pragma("unroll")                                                       \
        for (int k_ = 0; k_ < 6; ++k_)                                          \
            *(float4*)&Ln_[F0B + (4 * k_ + tq_) * P1B + c4_] = v0_[k_];         \
    }

#define ROWFMA(KK, OZP1, YRI, R)                                                \
    { const int base_ = (OZP1) * 9 + (2 - (YRI)) * 3;                           \
      acc[base_ + 0] += g0[KK]*R.x + fr[KK][0]*R.y + fr[KK][1]*R.z + fr[KK][2]*R.w; \
      acc[base_ + 1] += fr[KK][0]*R.x + fr[KK][1]*R.y + fr[KK][2]*R.z + fr[KK][3]*R.w; \
      acc[base_ + 2] += fr[KK][1]*R.x + fr[KK][2]*R.y + fr[KK][3]*R.z + g5[KK]*R.w; }

    if (wv == 3) STAGE_CH(0)
    __syncthreads();

    #pragma unroll 1
    for (int ch = 0; ch < 16; ++ch) {
        if (wv == 3) {
            if (ch + 1 < 16) STAGE_CH(ch + 1)
        } else {
            const float* Lb = &L[ch & 1][0];

            float fr[2][4];
            if (ident) {
                #pragma unroll
                for (int i = 0; i < 4; ++i) {
                    fr[0][i] = Lb[iA0 + i];
                    fr[1][i] = Lb[iA1 + i];
                }
            } else {
                #pragma unroll
                for (int k = 0; k < 2; ++k) {
                    #pragma unroll
                    for (int i = 0; i < 4; ++i) {
                        const int a = aB[k][i];
                        const float p00 = Lb[a], p01 = Lb[a + 1];
                        const float p10 = Lb[a + 4 * P1A], p11 = Lb[a + 4 * P1A + 1];
                        const float sLo = wAx[k][i] * p00 + wBx[k][i] * p01;
                        const float sHi = wAx[k][i] * p10 + wBx[k][i] * p11;
                        fr[k][i] = sHi + wZl[k][i] * (sLo - sHi);
                    }
                }
            }

            float g0[2], g5[2];
            #pragma unroll
            for (int k = 0; k < 2; ++k) {
                const float a_ = __shfl_up(fr[k][3], 1, 64);
                const float c_ = __shfl_down(fr[k][0], 1, 64);
                g0[k] = (tx == 0) ? 0.0f : a_;
                g5[k] = (tx == 15) ? 0.0f : c_;
            }

            __builtin_amdgcn_s_setprio(1);
            #pragma unroll
            for (int zri = 0; zri < 4; ++zri) {
                const float4 R0 = *(const float4*)&Lb[fb0 + (zri * 6 + 0) * P1B];
                const float4 R1 = *(const float4*)&Lb[fb0 + (zri * 6 + 1) * P1B];
                const float4 R2 = *(const float4*)&Lb[fb0 + (zri * 6 + 2) * P1B];
                if (zri == 0) { ROWFMA(0, 2, 0, R0) ROWFMA(0, 2, 1, R1) ROWFMA(0, 2, 2, R2) }
                if (zri == 1) { ROWFMA(0, 1, 0, R0) ROWFMA(0, 1, 1, R1) ROWFMA(0, 1, 2, R2)
                                ROWFMA(1, 2, 0, R0) ROWFMA(1, 2, 1, R1) ROWFMA(1, 2, 2, R2) }
                if (zri == 2) { ROWFMA(0, 0, 0, R0) ROWFMA(0, 0, 1, R1) ROWFMA(0, 0, 2, R2)
                                ROWFMA(1, 1, 0, R0) ROWFMA(1, 1, 1, R1) ROWFMA(1, 1, 2, R2) }
                if (zri == 3) { ROWFMA(1, 0, 0, R0) ROWFMA(1, 0, 1, R1) ROWFMA(1, 0, 2, R2) }
            }
            __builtin_amdgcn_s_setprio(0);
        }
        __syncthreads();
    }
#undef ROWFMA
#undef STAGE_CH

    if (wv < 3) {
        const int slot = (zt * 8 + yt) * 2 + chh;
        #pragma unroll 1
        for (int o = 0; o < 27; ++o) {
            float v = acc[o];
            #pragma unroll
            for (int d = 32; d >= 1; d >>= 1) v += __shfl_down(v, d, 64);
            if (lane == 0)
                partial[((size_t)((b * 3 + wv) * 27) + o) * NT2 + slot] = v;
        }
    }
}

// ---------------------------------------------------------------------------
// Kernel 2: grid(4) -- one block per batch. Reduce this batch's 81 partial
// rows (512 slots each), run the MLP, emit matrix + warp params + res vector.
// ---------------------------------------------------------------------------
__global__ __launch_bounds__(128) void k_mlp(const float* __restrict__ partial,
                                             const float* __restrict__ W1,
                                             const float* __restrict__ b1,
                                             const float* __restrict__ W2,
                                             const float* __restrict__ b2,
                                             const float* __restrict__ W3,
                                             const float* __restrict__ b3,
                                             float* __restrict__ out,
                                             float* __restrict__ params,
                                             float* __restrict__ resv)
{
    __shared__ float f[81];
    __shared__ float h1[128];
    __shared__ float h2[128];
    __shared__ float denom_s;
    __shared__ float r4[4];
    const int b = (int)blockIdx.x;
    const int tid = (int)threadIdx.x;

    if (tid < 81) {
        const float4* p = (const float4*)(partial + ((size_t)b * 81 + tid) * NT2);
        float s0 = 0.f, s1 = 0.f, s2 = 0.f, s3 = 0.f;
        #pragma unroll 4
        for (int i = 0; i < NT2 / 4; ++i) {
            const float4 v = p[i];
            s0 += v.x; s1 += v.y; s2 += v.z; s3 += v.w;
        }
        const float hv = ((s0 + s1) + (s2 + s3)) * INVC;
        f[tid] = (hv >= 0.0f) ? hv : 0.1f * hv;
    }
    __syncthreads();
    if (tid == 0) {
        float ss = 0.0f;
        for (int k = 0; k < 81; ++k) ss += f[k] * f[k];
        denom_s = 1e-6f + sqrtf(ss);
    }
    __syncthreads();
    if (tid < 81) f[tid] = f[tid] / denom_s;
    __syncthreads();
    {
        float a = b1[tid];
        const float* wr = W1 + tid * 81;
        for (int k = 0; k < 81; ++k) a += wr[k] * f[k];
        h1[tid] = (a >= 0.0f) ? a : 0.1f * a;
    }
    __syncthreads();
    {
        float a = b2[tid];
        const float* wr = W2 + tid * 128;
        for (int k = 0; k < 128; ++k) a += wr[k] * h1[k];
        h2[tid] = (a >= 0.0f) ? a : 0.1f * a;
    }
    __syncthreads();
    if (tid < 4) {
        float a = b3[tid];
        const float* wr = W3 + tid * 128;
        for (int k = 0; k < 128; ++k) a += wr[k] * h2[k];
        r4[tid] = a;
    }
    __syncthreads();
    if (tid == 0) {
        const float r_out = r4[0], yv = r4[1], xv = r4[2], zv = r4[3];
        const float t2 = r_out * D2R;
        const float c2 = cosf(t2), s2 = sinf(t2);
        float* m = out + 1 + b * 16;
        m[0] = c2;  m[1] = 0.0f; m[2] = s2;  m[3] = -xv;
        m[4] = 0.0f; m[5] = 1.0f; m[6] = 0.0f; m[7] = -yv;
        m[8] = -s2; m[9] = 0.0f; m[10] = c2; m[11] = -zv;
        m[12] = 0.0f; m[13] = 0.0f; m[14] = 0.0f; m[15] = 1.0f;
        params[b * 8 + 0] = c2;
        params[b * 8 + 1] = s2;
        params[b * 8 + 2] = c2 * xv - s2 * zv;
        params[b * 8 + 3] = yv;
        params[b * 8 + 4] = s2 * xv + c2 * zv;
        resv[b * 4 + 0] = -xv;
        resv[b * 4 + 1] = -yv;
        resv[b * 4 + 2] = -zv;
        resv[b * 4 + 3] = atan2f(s2, c2) * R2D;
    }
}

// ---------------------------------------------------------------------------
// Kernel 2.5: scalar loss from resv + ground truth.
// ---------------------------------------------------------------------------
__global__ __launch_bounds__(64) void k_loss(const float* __restrict__ resv,
                                             const float* __restrict__ camg,
                                             float* __restrict__ out)
{
    if (threadIdx.x == 0) {
        float tl2 = 0.0f, dl2 = 0.0f;
        for (int b = 0; b < NB; ++b) {
            const float* g = camg + b * 16;
            const float dx = resv[b * 4 + 0] - g[3];
            const float dy = resv[b * 4 + 1] - g[7];
            const float dz = resv[b * 4 + 2] - g[11];
            tl2 += dx * dx + dy * dy + dz * dz;
            const float dg = atan2f(g[2], g[10]) * R2D;
            const float dd = resv[b * 4 + 3] - dg;
            dl2 += dd * dd;
        }
        out[0] = tl2 * 0.25f + dl2 * 0.25f;
    }
}

// ---------------------------------------------------------------------------
// Kernel 3: warp feat1 by estimated transform -> feat1_warped (d_out + 65).
// 1 voxel/thread (r19's 4-voxel variant blew registers: 2.7x slower).
// XCD-chunked block remap: each XCD works one batch's contiguous z-range ->
// its L2 holds a compact feat1[b] slab for the 8-point gathers.
// Channel loop unroll 4: more gathers in flight (idx/w are loop-invariant).
// ---------------------------------------------------------------------------
__global__ __launch_bounds__(256) void k_warp(const float* __restrict__ feat1,
                                              const float* __restrict__ params,
                                              float* __restrict__ outw)
{
    // 2048 blocks flat; XCD x gets 256 consecutive nids (2 per batch's 128).
    const int flat = (int)blockIdx.y * 512 + (int)blockIdx.x;   // 0..2047
    const int nid  = (flat & 7) * 256 + (flat >> 3);
    const int b    = nid >> 9;                 // 0..3
    const int pblk = nid & 511;                // 0..511

    const int p = pblk * 256 + (int)threadIdx.x;
    const int z = p >> 11;
    const int y = (p >> 6) & 31;
    const int x = p & 63;

    const float cs = params[b * 8 + 0], sn = params[b * 8 + 1];
    const float tpx = params[b * 8 + 2], tpy = params[b * 8 + 3], tpz = params[b * 8 + 4];

    const float rx = (float)x - 31.5f;
    const float ry = (float)y - 15.5f;
    const float rz = (float)z - 31.5f;
    const float sx = cs * rx - sn * rz + tpx + 31.5f;
    const float sy = ry + tpy + 15.5f;
    const float sz = sn * rx + cs * rz + tpz + 31.5f;

    const float xf = floorf(sx), yf = floorf(sy), zf = floorf(sz);
    const float fx = sx - xf, fy = sy - yf, fz = sz - zf;
    const int ix = (int)xf, iy = (int)yf, iz = (int)zf;

    const float wx[2] = {1.0f - fx, fx};
    const float wy[2] = {1.0f - fy, fy};
    const float wz[2] = {1.0f - fz, fz};
    const int xs[2] = {min(max(ix, 0), 63), min(max(ix + 1, 0), 63)};
    const int ys[2] = {min(max(iy, 0), 31), min(max(iy + 1, 0), 31)};
    const int zs[2] = {min(max(iz, 0), 63), min(max(iz + 1, 0), 63)};
    const bool vx[2] = {(unsigned)ix < 64u, (unsigned)(ix + 1) < 64u};
    const bool vy[2] = {(unsigned)iy < 32u, (unsigned)(iy + 1) < 32u};
    const bool vz[2] = {(unsigned)iz < 64u, (unsigned)(iz + 1) < 64u};

    int idx[8]; float w[8];
    int q = 0;
    #pragma unroll
    for (int dz = 0; dz < 2; ++dz)
        #pragma unroll
        for (int dy = 0; dy < 2; ++dy)
            #pragma unroll
            for (int dx = 0; dx < 2; ++dx) {
                idx[q] = zs[dz] * 2048 + ys[dy] * 64 + xs[dx];
                w[q] = (vx[dx] && vy[dy] && vz[dz]) ? wx[dx] * wy[dy] * wz[dz] : 0.0f;
                ++q;
            }

    const float* f1b = feat1 + (size_t)b * NCH * CHV;
    float* ob = outw + (size_t)b * NCH * CHV;
    #pragma unroll 4
    for (int c = 0; c < NCH; ++c) {
        const float* f1c = f1b + (size_t)c * CHV;
        float a = 0.0f;
        #pragma unroll
        for (int k = 0; k < 8; ++k) a += w[k] * f1c[idx[k]];
        ob[(size_t)c * CHV + p] = a;
    }
}

// ---------------------------------------------------------------------------
extern "C" void kernel_launch(void* const* d_in, const int* in_sizes, int n_in,
                              void* d_out, int out_size, void* d_ws, size_t ws_size,
                              hipStream_t stream)
{
    (void)in_sizes; (void)n_in; (void)out_size; (void)ws_size;
    const float* feat0 = (const float*)d_in[0];
    const float* feat1 = (const float*)d_in[1];
    const float* camg  = (const float*)d_in[2];
    const float* W1 = (const float*)d_in[3];
    const float* b1 = (const float*)d_in[4];
    const float* W2 = (const float*)d_in[5];
    const float* b2 = (const float*)d_in[6];
    const float* W3 = (const float*)d_in[7];
    const float* b3 = (const float*)d_in[8];
    float* out = (float*)d_out;

    float* partial = (float*)d_ws;                 // 324*512 floats ~ 663 KB
    float* params  = partial + 324 * NT2;          // 32 floats
    float* resv    = params + 32;                  // 16 floats

    hipLaunchKernelGGL(k_heat, dim3(2048), dim3(256), 0, stream,
                       feat0, feat1, partial);
    hipLaunchKernelGGL(k_mlp, dim3(4), dim3(128), 0, stream,
                       partial, W1, b1, W2, b2, W3, b3, out, params, resv);
    hipLaunchKernelGGL(k_loss, dim3(1), dim3(64), 0, stream, resv, camg, out);
    hipLaunchKernelGGL(k_warp, dim3(512, 4), dim3(256), 0, stream,
                       feat1, params, out + 65);
}